// Round 1
// baseline (1758.913 us; speedup 1.0000x reference)
//
#include <hip/hip_runtime.h>
#include <math.h>

// Problem constants
#define B_   16
#define QL_  512
#define VL_  512
#define HID_ 1024
#define NH_  4
#define CH_  10
#define DIM_ 256

// ---------------- generic 128x128x8 f32 GEMM ----------------
// C = scale*(A@B[^T]) + bias (+C if accum) (tanh at end if requested)
// flags: 1 = accumulate into existing C, 2 = tanh, 4 = B is (N x K) row-major (use B^T)
// batch z decomposed as zm = z % WB, zd = z / WB; pointer offsets a1*zm + a2*zd etc.
#define BM 128
#define BN 128
#define BK 8

__global__ __launch_bounds__(256)
void gemm_f32(const float* __restrict__ A, const float* __restrict__ B,
              float* __restrict__ C, const float* __restrict__ bias,
              int M, int N, int K, int lda, int ldb, int ldc,
              long long a1, long long a2, long long b1, long long b2,
              long long c1, long long c2, int WB,
              float scale, int flags)
{
    int z = blockIdx.z;
    int zm = z % WB, zd = z / WB;
    A += a1 * zm + a2 * zd;
    B += b1 * zm + b2 * zd;
    C += c1 * zm + c2 * zd;

    int brow = blockIdx.y * BM;
    int bcol = blockIdx.x * BN;

    __shared__ float As[BK][BM + 4];
    __shared__ float Bs[BK][BN + 4];

    int t  = threadIdx.x;
    int tx = t & 15;          // micro-tile col group
    int ty = t >> 4;          // micro-tile row group

    float acc[8][8] = {};

    int arow  = t >> 1;           // 0..127
    int apart = (t & 1) * 4;      // 0 or 4

    for (int k0 = 0; k0 < K; k0 += BK) {
        // A tile: 128 rows x 8 k
        {
            const float* ap = A + (long long)(brow + arow) * lda + k0 + apart;
            float4 v = *(const float4*)ap;
            As[apart + 0][arow] = v.x;
            As[apart + 1][arow] = v.y;
            As[apart + 2][arow] = v.z;
            As[apart + 3][arow] = v.w;
        }
        // B tile: 8 k x 128 cols
        if (!(flags & 4)) {
            int bro = t >> 5;         // 0..7
            int bco = (t & 31) * 4;   // 0..124
            const float* bp = B + (long long)(k0 + bro) * ldb + bcol + bco;
            float4 v = *(const float4*)bp;
            *(float4*)&Bs[bro][bco] = v;
        } else {
            // B^T: element (k, n) at B[n*ldb + k]
            int nrow = t >> 1;
            const float* bp = B + (long long)(bcol + nrow) * ldb + k0 + apart;
            float4 v = *(const float4*)bp;
            Bs[apart + 0][nrow] = v.x;
            Bs[apart + 1][nrow] = v.y;
            Bs[apart + 2][nrow] = v.z;
            Bs[apart + 3][nrow] = v.w;
        }
        __syncthreads();

        #pragma unroll
        for (int k = 0; k < BK; ++k) {
            float a[8], b[8];
            *(float4*)&a[0] = *(const float4*)&As[k][ty * 8];
            *(float4*)&a[4] = *(const float4*)&As[k][ty * 8 + 4];
            *(float4*)&b[0] = *(const float4*)&Bs[k][tx * 8];
            *(float4*)&b[4] = *(const float4*)&Bs[k][tx * 8 + 4];
            #pragma unroll
            for (int i = 0; i < 8; ++i)
                #pragma unroll
                for (int j = 0; j < 8; ++j)
                    acc[i][j] += a[i] * b[j];
        }
        __syncthreads();
    }

    // epilogue
    #pragma unroll
    for (int i = 0; i < 8; ++i) {
        int r = brow + ty * 8 + i;
        #pragma unroll
        for (int j = 0; j < 8; ++j) {
            int c = bcol + tx * 8 + j;
            float vL = acc[i][j] * scale;
            if (bias) vL += bias[c];
            float* cp = C + (long long)r * ldc + c;
            if (flags & 1) vL += *cp;
            if (flags & 2) vL = tanhf(vL);
            *cp = vL;
        }
    }
}

// ---------------- conv features: conv[r][l][c] = sum_k prev[r][l+k-1]*w[c][k] + cb[c] ----------------
__global__ __launch_bounds__(256)
void conv_feats(const float* __restrict__ prev, const float* __restrict__ cw,
                const float* __restrict__ cb, float* __restrict__ out)
{
    int r = blockIdx.x;                       // 0..63 (= b*NH + h)
    int l = blockIdx.y * 256 + threadIdx.x;   // 0..511
    const float* p = prev + (long long)r * VL_;
    float xm = (l > 0)        ? p[l - 1] : 0.f;
    float x0 = p[l];
    float xp = (l < VL_ - 1)  ? p[l + 1] : 0.f;
    float* o = out + ((long long)r * VL_ + l) * CH_;
    #pragma unroll
    for (int c = 0; c < CH_; ++c)
        o[c] = xm * cw[c * 3 + 0] + x0 * cw[c * 3 + 1] + xp * cw[c * 3 + 2] + cb[c];
}

// ---------------- fold biases: bqq = bq_h@swq + sbq ; bkk = bias_h@swk + sbk ; bvv = bias_h@swv + sbv ----------------
__global__ __launch_bounds__(256)
void fold_bias(const float* __restrict__ bq, const float* __restrict__ sbq, const float* __restrict__ swq,
               const float* __restrict__ bias, const float* __restrict__ sbk, const float* __restrict__ swk,
               const float* __restrict__ sbv, const float* __restrict__ swv,
               float* __restrict__ bqq, float* __restrict__ bkk, float* __restrict__ bvv)
{
    int idx = blockIdx.x * 256 + threadIdx.x;   // 0..1023
    int h = idx >> 8, d = idx & 255;
    float s1 = 0.f, s2 = 0.f, s3 = 0.f;
    for (int j = 0; j < DIM_; ++j) {
        float bqj = bq[h * DIM_ + j];
        float bj  = bias[h * DIM_ + j];
        s1 += bqj * swq[j * DIM_ + d];
        s2 += bj  * swk[j * DIM_ + d];
        s3 += bj  * swv[j * DIM_ + d];
    }
    bqq[idx] = s1 + sbq[d];
    bkk[idx] = s2 + sbk[d];
    bvv[idx] = s3 + sbv[d];
}

// ---------------- fold Wloc: WK = Wloc@swk, WV = Wloc@swv (10x256 each) ----------------
__global__ __launch_bounds__(256)
void fold_wloc(const float* __restrict__ Wloc, const float* __restrict__ swk,
               const float* __restrict__ swv, float* __restrict__ WK, float* __restrict__ WV)
{
    int idx = blockIdx.x * 256 + threadIdx.x;   // 0..2559
    int c = idx >> 8, d = idx & 255;
    float s1 = 0.f, s2 = 0.f;
    for (int j = 0; j < DIM_; ++j) {
        float w = Wloc[c * DIM_ + j];
        s1 += w * swk[j * DIM_ + d];
        s2 += w * swv[j * DIM_ + d];
    }
    WK[idx] = s1;
    WV[idx] = s2;
}

// ---------------- rank-10 loc correction: kk/vv[b,l,h*256+d] += sum_c conv[b,h,l,c]*W[c][d] ----------------
__global__ __launch_bounds__(256)
void add_locproj(const float* __restrict__ conv, const float* __restrict__ WK,
                 const float* __restrict__ WV, float* __restrict__ kk, float* __restrict__ vv)
{
    int id = blockIdx.x;          // 0..(64*512-1) = r*512 + l, r = b*NH + h
    int l = id & 511;
    int r = id >> 9;
    int h = r & 3;
    int b = r >> 2;
    int d = threadIdx.x;

    __shared__ float c_sh[CH_];
    if (threadIdx.x < CH_) c_sh[threadIdx.x] = conv[(long long)id * CH_ + threadIdx.x];
    __syncthreads();

    float s1 = 0.f, s2 = 0.f;
    #pragma unroll
    for (int c = 0; c < CH_; ++c) {
        float cv = c_sh[c];
        s1 += cv * WK[c * DIM_ + d];
        s2 += cv * WV[c * DIM_ + d];
    }
    long long off = ((long long)(b * VL_ + l)) * HID_ + h * DIM_ + d;
    kk[off] += s1;
    vv[off] += s2;
}

// ---------------- row softmax over 512, in place ----------------
__global__ __launch_bounds__(256)
void softmax_rows(float* __restrict__ s)
{
    long long row = blockIdx.x;
    float* p = s + row * (long long)VL_;
    int t = threadIdx.x;
    float2 v = *(float2*)(p + 2 * t);

    float m = fmaxf(v.x, v.y);
    #pragma unroll
    for (int o = 32; o > 0; o >>= 1) m = fmaxf(m, __shfl_down(m, o));
    __shared__ float redm[4];
    __shared__ float reds[4];
    int wave = t >> 6, lane = t & 63;
    if (lane == 0) redm[wave] = m;
    __syncthreads();
    if (t == 0) redm[0] = fmaxf(fmaxf(redm[0], redm[1]), fmaxf(redm[2], redm[3]));
    __syncthreads();
    m = redm[0];

    float e0 = __expf(v.x - m), e1 = __expf(v.y - m);
    float sum = e0 + e1;
    #pragma unroll
    for (int o = 32; o > 0; o >>= 1) sum += __shfl_down(sum, o);
    if (lane == 0) reds[wave] = sum;
    __syncthreads();
    if (t == 0) reds[0] = reds[0] + reds[1] + reds[2] + reds[3];
    __syncthreads();
    float inv = 1.0f / reds[0];

    float2 o2;
    o2.x = e0 * inv;
    o2.y = e1 * inv;
    *(float2*)(p + 2 * t) = o2;
}

extern "C" void kernel_launch(void* const* d_in, const int* in_sizes, int n_in,
                              void* d_out, int out_size, void* d_ws, size_t ws_size,
                              hipStream_t stream)
{
    (void)in_sizes; (void)n_in; (void)out_size; (void)ws_size;

    const float* query = (const float*)d_in[0];
    const float* value = (const float*)d_in[1];
    const float* prev  = (const float*)d_in[2];
    const float* convw = (const float*)d_in[3];
    const float* convb = (const float*)d_in[4];
    const float* Wq    = (const float*)d_in[5];
    const float* bq    = (const float*)d_in[6];
    const float* Wv    = (const float*)d_in[7];
    const float* Wloc  = (const float*)d_in[8];
    const float* bias  = (const float*)d_in[9];
    const float* Wout  = (const float*)d_in[10];
    const float* bout  = (const float*)d_in[11];
    const float* swq   = (const float*)d_in[12];
    const float* sbq   = (const float*)d_in[13];
    const float* swk   = (const float*)d_in[14];
    const float* sbk   = (const float*)d_in[15];
    const float* swv   = (const float*)d_in[16];
    const float* sbv   = (const float*)d_in[17];

    float* out_buf  = (float*)d_out;                              // (B,QL,HID)
    float* attn_buf = out_buf + (long long)B_ * QL_ * HID_;       // (64,512,512)

    float* ws = (float*)d_ws;
    float* wqq  = ws; ws += 1048576;     // (1024,1024) folded Wq*swq per head-col-block
    float* wvk  = ws; ws += 1048576;     // (1024,1024) folded Wv*swk
    float* wvv  = ws; ws += 1048576;     // (1024,1024) folded Wv*swv
    float* bqq  = ws; ws += 1024;
    float* bkk  = ws; ws += 1024;
    float* bvv  = ws; ws += 1024;
    float* wlK  = ws; ws += 2560;        // (10,256)
    float* wlV  = ws; ws += 2560;        // (10,256)
    float* conv = ws; ws += 327680;      // (64,512,10)
    float* qq   = ws; ws += 8388608;     // (B*QL, HID) viewed per head
    float* kk   = ws; ws += 8388608;
    float* vv   = ws; ws += 8388608;
    float* ctx  = ws; ws += 8388608;     // (B,QL,HID) merged-head context

    // small precomputes
    conv_feats<<<dim3(64, 2), 256, 0, stream>>>(prev, convw, convb, conv);
    fold_bias<<<4, 256, 0, stream>>>(bq, sbq, swq, bias, sbk, swk, sbv, swv, bqq, bkk, bvv);
    fold_wloc<<<10, 256, 0, stream>>>(Wloc, swk, swv, wlK, wlV);

    // folded weights: per head h, Wqq[:, h*256:(h+1)*256] = Wq[:, h*256:] @ swq, etc.
    gemm_f32<<<dim3(2, 8, 4), 256, 0, stream>>>(Wq, swq, wqq, nullptr, 1024, 256, 256,
        1024, 256, 1024, 256, 0, 0, 0, 256, 0, 4, 1.0f, 0);
    gemm_f32<<<dim3(2, 8, 4), 256, 0, stream>>>(Wv, swk, wvk, nullptr, 1024, 256, 256,
        1024, 256, 1024, 256, 0, 0, 0, 256, 0, 4, 1.0f, 0);
    gemm_f32<<<dim3(2, 8, 4), 256, 0, stream>>>(Wv, swv, wvv, nullptr, 1024, 256, 256,
        1024, 256, 1024, 256, 0, 0, 0, 256, 0, 4, 1.0f, 0);

    // qq = query @ Wqq + bqq ; kk/vv = value @ Wvk/Wvv + bkk/bvv
    gemm_f32<<<dim3(8, 64, 1), 256, 0, stream>>>(query, wqq, qq, bqq, 8192, 1024, 1024,
        1024, 1024, 1024, 0, 0, 0, 0, 0, 0, 1, 1.0f, 0);
    gemm_f32<<<dim3(8, 64, 1), 256, 0, stream>>>(value, wvk, kk, bkk, 8192, 1024, 1024,
        1024, 1024, 1024, 0, 0, 0, 0, 0, 0, 1, 1.0f, 0);
    gemm_f32<<<dim3(8, 64, 1), 256, 0, stream>>>(value, wvv, vv, bvv, 8192, 1024, 1024,
        1024, 1024, 1024, 0, 0, 0, 0, 0, 0, 1, 1.0f, 0);

    // rank-10 location correction into kk, vv
    add_locproj<<<32768, 256, 0, stream>>>(conv, wlK, wlV, kk, vv);

    // scores = qq @ kk^T / 16  -> attn region of d_out   (batch n = h*16 + b)
    gemm_f32<<<dim3(4, 4, 64), 256, 0, stream>>>(qq, kk, attn_buf, nullptr, 512, 512, 256,
        1024, 1024, 512,
        524288, 256,          // A: + b*QL*HID + h*256
        524288, 256,          // B: + b*VL*HID + h*256   (trans)
        262144, 4194304,      // C: + b*QL*VL + h*B*QL*VL
        16, 0.0625f, 4);

    softmax_rows<<<32768, 256, 0, stream>>>(attn_buf);

    // ctx = attn @ vv   (per n), written merged as (B,QL,HID)
    gemm_f32<<<dim3(2, 4, 64), 256, 0, stream>>>(attn_buf, vv, ctx, nullptr, 512, 256, 512,
        512, 1024, 1024,
        262144, 4194304,      // A: + b*QL*VL + h*B*QL*VL
        524288, 256,          // B: + b*VL*HID + h*256
        524288, 256,          // C: + b*QL*HID + h*256
        16, 1.0f, 0);

    // out = tanh(ctx @ Wout[:1024] + query @ Wout[1024:] + bout)
    gemm_f32<<<dim3(8, 64, 1), 256, 0, stream>>>(ctx, Wout, out_buf, bout, 8192, 1024, 1024,
        1024, 1024, 1024, 0, 0, 0, 0, 0, 0, 1, 1.0f, 0);
    gemm_f32<<<dim3(8, 64, 1), 256, 0, stream>>>(query, Wout + 1048576, out_buf, nullptr, 8192, 1024, 1024,
        1024, 1024, 1024, 0, 0, 0, 0, 0, 0, 1, 1.0f, 3);
}

// Round 2
// 532.207 us; speedup vs baseline: 3.3049x; 3.3049x over previous
//
#include <hip/hip_runtime.h>
#include <math.h>

// Problem constants
#define B_   16
#define QL_  512
#define VL_  512
#define HID_ 1024
#define NH_  4
#define CH_  10
#define DIM_ 256

typedef __attribute__((ext_vector_type(4))) float f32x4;
typedef __attribute__((ext_vector_type(8))) short bf16x8;

__device__ __forceinline__ ushort f2bf(float f) {
    union { float f; uint32_t u; } c; c.f = f;
    uint32_t u = c.u;
    u += 0x7fffu + ((u >> 16) & 1u);
    return (ushort)(u >> 16);
}

__device__ __forceinline__ void gload16(const void* g, void* l) {
    __builtin_amdgcn_global_load_lds((const __attribute__((address_space(1))) void*)g,
                                     (__attribute__((address_space(3))) void*)l,
                                     16, 0, 0);
}

// ================= MFMA bf16 GEMM: C = op((A @ Bt^T) + bias) * scale =================
// A: M x K bf16 row-major (lda). Bt: N x K bf16 row-major (ldb). Tiles full (M%128==N%128==0, K%32==0).
// flags: 1 = C is bf16, 2 = tanh. batch z: zm=z%WB, zd=z/WB offsets.
__global__ __launch_bounds__(256)
void gemm_bf16(const ushort* __restrict__ A, const ushort* __restrict__ Bt,
               void* __restrict__ Cv, const float* __restrict__ bias,
               int K, int lda, int ldb, int ldc,
               long long a1, long long a2, long long b1, long long b2,
               long long c1, long long c2, int WB,
               float post_scale, int flags)
{
    __shared__ ushort As[128 * 32];
    __shared__ ushort Bs[128 * 32];

    int z = blockIdx.z;
    int zm = z % WB, zd = z / WB;
    A  += a1 * zm + a2 * zd;
    Bt += b1 * zm + b2 * zd;
    long long coff = c1 * (long long)zm + c2 * (long long)zd;

    int brow = blockIdx.y * 128;
    int bcol = blockIdx.x * 128;
    int t = threadIdx.x;
    int lane = t & 63, w = t >> 6;
    int wr = (w >> 1) * 64, wc = (w & 1) * 64;

    // staging: chunk i in 0..511 covers LDS bytes i*16 = row (i>>2), k-part (i&3)*8
    const ushort* ga0 = A  + (long long)(brow + (t >> 2)) * lda + (t & 3) * 8;
    const ushort* ga1 = ga0 + (long long)64 * lda;
    const ushort* gb0 = Bt + (long long)(bcol + (t >> 2)) * ldb + (t & 3) * 8;
    const ushort* gb1 = gb0 + (long long)64 * ldb;
    ushort* la = As + t * 8;
    ushort* lb = Bs + t * 8;

    f32x4 acc[4][4] = {};

    for (int k0 = 0; k0 < K; k0 += 32) {
        gload16(ga0 + k0, la);
        gload16(ga1 + k0, la + 2048);
        gload16(gb0 + k0, lb);
        gload16(gb1 + k0, lb + 2048);
        __syncthreads();

        const bf16x8* ap = (const bf16x8*)(As + (wr + (lane & 15)) * 32 + (lane >> 4) * 8);
        const bf16x8* bp = (const bf16x8*)(Bs + (wc + (lane & 15)) * 32 + (lane >> 4) * 8);
        bf16x8 af[4], bfr[4];
        #pragma unroll
        for (int m = 0; m < 4; ++m) af[m] = ap[m * 64];    // 16 rows * 32 k / 8 = 64 vec units
        #pragma unroll
        for (int n = 0; n < 4; ++n) bfr[n] = bp[n * 64];
        #pragma unroll
        for (int m = 0; m < 4; ++m)
            #pragma unroll
            for (int n = 0; n < 4; ++n)
                acc[m][n] = __builtin_amdgcn_mfma_f32_16x16x32_bf16(af[m], bfr[n], acc[m][n], 0, 0, 0);
        __syncthreads();
    }

    float*  Cf = (float*)Cv + coff;
    ushort* Cb = (ushort*)Cv + coff;
    #pragma unroll
    for (int m = 0; m < 4; ++m) {
        int r0 = brow + wr + m * 16 + (lane >> 4) * 4;
        #pragma unroll
        for (int n = 0; n < 4; ++n) {
            int c = bcol + wc + n * 16 + (lane & 15);
            float bv = bias ? bias[c] : 0.0f;
            #pragma unroll
            for (int j = 0; j < 4; ++j) {
                float v = (acc[m][n][j] + bv) * post_scale;
                if (flags & 2) v = tanhf(v);
                long long idx = (long long)(r0 + j) * ldc + c;
                if (flags & 1) Cb[idx] = f2bf(v);
                else           Cf[idx] = v;
            }
        }
    }
}

// ================= f32 GEMM (kept for tiny folded-weight products) =================
#define BM 128
#define BN 128
#define BK 8
__global__ __launch_bounds__(256)
void gemm_f32(const float* __restrict__ A, const float* __restrict__ B,
              float* __restrict__ C, const float* __restrict__ bias,
              int M, int N, int K, int lda, int ldb, int ldc,
              long long a1, long long a2, long long b1, long long b2,
              long long c1, long long c2, int WB,
              float scale, int flags)
{
    int z = blockIdx.z;
    int zm = z % WB, zd = z / WB;
    A += a1 * zm + a2 * zd;
    B += b1 * zm + b2 * zd;
    C += c1 * zm + c2 * zd;

    int brow = blockIdx.y * BM;
    int bcol = blockIdx.x * BN;

    __shared__ float As[BK][BM + 4];
    __shared__ float Bs[BK][BN + 4];

    int t  = threadIdx.x;
    int tx = t & 15;
    int ty = t >> 4;

    float acc[8][8] = {};

    int arow  = t >> 1;
    int apart = (t & 1) * 4;

    for (int k0 = 0; k0 < K; k0 += BK) {
        {
            const float* ap = A + (long long)(brow + arow) * lda + k0 + apart;
            float4 v = *(const float4*)ap;
            As[apart + 0][arow] = v.x;
            As[apart + 1][arow] = v.y;
            As[apart + 2][arow] = v.z;
            As[apart + 3][arow] = v.w;
        }
        {
            int bro = t >> 5;
            int bco = (t & 31) * 4;
            const float* bp = B + (long long)(k0 + bro) * ldb + bcol + bco;
            float4 v = *(const float4*)bp;
            *(float4*)&Bs[bro][bco] = v;
        }
        __syncthreads();

        #pragma unroll
        for (int k = 0; k < BK; ++k) {
            float a[8], b[8];
            *(float4*)&a[0] = *(const float4*)&As[k][ty * 8];
            *(float4*)&a[4] = *(const float4*)&As[k][ty * 8 + 4];
            *(float4*)&b[0] = *(const float4*)&Bs[k][tx * 8];
            *(float4*)&b[4] = *(const float4*)&Bs[k][tx * 8 + 4];
            #pragma unroll
            for (int i = 0; i < 8; ++i)
                #pragma unroll
                for (int j = 0; j < 8; ++j)
                    acc[i][j] += a[i] * b[j];
        }
        __syncthreads();
    }

    #pragma unroll
    for (int i = 0; i < 8; ++i) {
        int r = brow + ty * 8 + i;
        #pragma unroll
        for (int j = 0; j < 8; ++j) {
            int c = bcol + tx * 8 + j;
            float vL = acc[i][j] * scale;
            if (bias) vL += bias[c];
            float* cp = C + (long long)r * ldc + c;
            if (flags & 1) vL += *cp;
            if (flags & 2) vL = tanhf(vL);
            *cp = vL;
        }
    }
}

// ================= small kernels =================
__global__ __launch_bounds__(256)
void conv_feats(const float* __restrict__ prev, const float* __restrict__ cw,
                const float* __restrict__ cb, float* __restrict__ out)
{
    int r = blockIdx.x;
    int l = blockIdx.y * 256 + threadIdx.x;
    const float* p = prev + (long long)r * VL_;
    float xm = (l > 0)       ? p[l - 1] : 0.f;
    float x0 = p[l];
    float xp = (l < VL_ - 1) ? p[l + 1] : 0.f;
    float* o = out + ((long long)r * VL_ + l) * CH_;
    #pragma unroll
    for (int c = 0; c < CH_; ++c)
        o[c] = xm * cw[c * 3 + 0] + x0 * cw[c * 3 + 1] + xp * cw[c * 3 + 2] + cb[c];
}

__global__ __launch_bounds__(256)
void fold_bias(const float* __restrict__ bq, const float* __restrict__ sbq, const float* __restrict__ swq,
               const float* __restrict__ bias, const float* __restrict__ sbk, const float* __restrict__ swk,
               const float* __restrict__ sbv, const float* __restrict__ swv,
               float* __restrict__ bqq, float* __restrict__ bkk, float* __restrict__ bvv)
{
    int idx = blockIdx.x * 256 + threadIdx.x;
    int h = idx >> 8, d = idx & 255;
    float s1 = 0.f, s2 = 0.f, s3 = 0.f;
    for (int j = 0; j < DIM_; ++j) {
        float bqj = bq[h * DIM_ + j];
        float bj  = bias[h * DIM_ + j];
        s1 += bqj * swq[j * DIM_ + d];
        s2 += bj  * swk[j * DIM_ + d];
        s3 += bj  * swv[j * DIM_ + d];
    }
    bqq[idx] = s1 + sbq[d];
    bkk[idx] = s2 + sbk[d];
    bvv[idx] = s3 + sbv[d];
}

__global__ __launch_bounds__(256)
void fold_wloc(const float* __restrict__ Wloc, const float* __restrict__ swk,
               const float* __restrict__ swv, float* __restrict__ WK, float* __restrict__ WV)
{
    int idx = blockIdx.x * 256 + threadIdx.x;
    int c = idx >> 8, d = idx & 255;
    float s1 = 0.f, s2 = 0.f;
    for (int j = 0; j < DIM_; ++j) {
        float w = Wloc[c * DIM_ + j];
        s1 += w * swk[j * DIM_ + d];
        s2 += w * swv[j * DIM_ + d];
    }
    WK[idx] = s1;
    WV[idx] = s2;
}

// cast 1024-col f32 rows to bf16 rows with output leading dim ld_out
__global__ __launch_bounds__(256)
void cast_rows(const float* __restrict__ in, ushort* __restrict__ out, int ld_out)
{
    long long idx = (long long)blockIdx.x * 256 + threadIdx.x;
    long long row = idx >> 8;
    int c4 = (int)(idx & 255) * 4;
    float4 v = *(const float4*)&in[row * 1024 + c4];
    ushort4 o;
    o.x = f2bf(v.x); o.y = f2bf(v.y); o.z = f2bf(v.z); o.w = f2bf(v.w);
    *(ushort4*)&out[row * ld_out + c4] = o;
}

// out[c][r] = bf16(in[r][c]); in: R x C f32, out: C x R bf16. 64x64 tiles.
__global__ __launch_bounds__(256)
void transpose_cast(const float* __restrict__ in, ushort* __restrict__ out, int R, int C)
{
    __shared__ float tile[64][65];
    int r0 = blockIdx.y * 64, c0 = blockIdx.x * 64;
    int t = threadIdx.x;
    int tr = t >> 2, tc = (t & 3) * 16;
    const float* ip = in + (long long)(r0 + tr) * C + c0 + tc;
    #pragma unroll
    for (int i = 0; i < 4; ++i) {
        float4 v = *(const float4*)(ip + i * 4);
        tile[tr][tc + i * 4 + 0] = v.x;
        tile[tr][tc + i * 4 + 1] = v.y;
        tile[tr][tc + i * 4 + 2] = v.z;
        tile[tr][tc + i * 4 + 3] = v.w;
    }
    __syncthreads();
    int cl = t >> 2, rl = (t & 3) * 16;
    ushort* op = out + (long long)(c0 + cl) * R + r0 + rl;
    #pragma unroll
    for (int i = 0; i < 16; ++i) op[i] = f2bf(tile[rl + i][cl]);
}

// kkb[r][c] = bf16(kk[r][c] + sum_cc conv[(b*4+h)*512+l][cc] * wlK[cc][c&255])
__global__ __launch_bounds__(256)
void finish_kk(const float* __restrict__ kk, const float* __restrict__ conv,
               const float* __restrict__ wlK, ushort* __restrict__ out)
{
    int r = blockIdx.x;          // 0..8191 = b*512 + l
    int b = r >> 9, l = r & 511;
    int t = threadIdx.x;
    int h  = (t * 4) >> 8;
    int d0 = (t * 4) & 255;
    __shared__ float csh[4][CH_];
    if (t < 4 * CH_) csh[t / CH_][t % CH_] =
        conv[((long long)((b * 4 + t / CH_) * 512 + l)) * CH_ + (t % CH_)];
    __syncthreads();
    float4 v = *(const float4*)&kk[(long long)r * 1024 + t * 4];
    float s0 = 0.f, s1 = 0.f, s2 = 0.f, s3 = 0.f;
    #pragma unroll
    for (int cc = 0; cc < CH_; ++cc) {
        float cv = csh[h][cc];
        const float* wr_ = &wlK[cc * 256 + d0];
        s0 += cv * wr_[0]; s1 += cv * wr_[1]; s2 += cv * wr_[2]; s3 += cv * wr_[3];
    }
    ushort4 o;
    o.x = f2bf(v.x + s0); o.y = f2bf(v.y + s1); o.z = f2bf(v.z + s2); o.w = f2bf(v.w + s3);
    *(ushort4*)&out[(long long)r * 1024 + t * 4] = o;
}

// vvT[h*256+d][b*512+l] = bf16(vv[b*512+l][h*256+d] + loc_v);  out ld = 8192
__global__ __launch_bounds__(256)
void finish_vvT(const float* __restrict__ vv, const float* __restrict__ conv,
                const float* __restrict__ wlV, ushort* __restrict__ out)
{
    __shared__ float tile[64][65];
    int r0 = blockIdx.x * 64;        // vv row tile (0..8191)
    int c0 = blockIdx.y * 64;        // vv col tile (0..1023)
    int t = threadIdx.x;
    int tr = t >> 2, tc = (t & 3) * 16;
    int rg = r0 + tr;
    int b = rg >> 9, l = rg & 511;
    int h = c0 >> 8;
    int dl0 = (c0 & 255) + tc;
    float cr[CH_];
    #pragma unroll
    for (int cc = 0; cc < CH_; ++cc)
        cr[cc] = conv[((long long)((b * 4 + h) * 512 + l)) * CH_ + cc];
    #pragma unroll
    for (int i = 0; i < 4; ++i) {
        float4 v = *(const float4*)&vv[(long long)rg * 1024 + c0 + tc + i * 4];
        float vs[4] = {v.x, v.y, v.z, v.w};
        #pragma unroll
        for (int e = 0; e < 4; ++e) {
            int d = dl0 + i * 4 + e;
            float s = 0.f;
            #pragma unroll
            for (int cc = 0; cc < CH_; ++cc) s += cr[cc] * wlV[cc * 256 + d];
            tile[tr][tc + i * 4 + e] = vs[e] + s;
        }
    }
    __syncthreads();
    int cl = t >> 2, rl = (t & 3) * 16;
    ushort* op = out + (long long)(c0 + cl) * 8192 + r0 + rl;
    #pragma unroll
    for (int i = 0; i < 16; ++i) op[i] = f2bf(tile[rl + i][cl]);
}

// row softmax over 512, in place (f32) + bf16 copy
__global__ __launch_bounds__(256)
void softmax_rows(float* __restrict__ s, ushort* __restrict__ sb)
{
    long long row = blockIdx.x;
    float* p = s + row * (long long)VL_;
    int t = threadIdx.x;
    float2 v = *(float2*)(p + 2 * t);

    float m = fmaxf(v.x, v.y);
    #pragma unroll
    for (int o = 32; o > 0; o >>= 1) m = fmaxf(m, __shfl_down(m, o));
    __shared__ float redm[4];
    __shared__ float reds[4];
    int wave = t >> 6, lane = t & 63;
    if (lane == 0) redm[wave] = m;
    __syncthreads();
    if (t == 0) redm[0] = fmaxf(fmaxf(redm[0], redm[1]), fmaxf(redm[2], redm[3]));
    __syncthreads();
    m = redm[0];

    float e0 = __expf(v.x - m), e1 = __expf(v.y - m);
    float sum = e0 + e1;
    #pragma unroll
    for (int o = 32; o > 0; o >>= 1) sum += __shfl_down(sum, o);
    if (lane == 0) reds[wave] = sum;
    __syncthreads();
    if (t == 0) reds[0] = reds[0] + reds[1] + reds[2] + reds[3];
    __syncthreads();
    float inv = 1.0f / reds[0];

    float2 o2;
    o2.x = e0 * inv;
    o2.y = e1 * inv;
    *(float2*)(p + 2 * t) = o2;
    ushort2 ob;
    ob.x = f2bf(o2.x); ob.y = f2bf(o2.y);
    *(ushort2*)&sb[row * VL_ + 2 * t] = ob;
}

extern "C" void kernel_launch(void* const* d_in, const int* in_sizes, int n_in,
                              void* d_out, int out_size, void* d_ws, size_t ws_size,
                              hipStream_t stream)
{
    (void)in_sizes; (void)n_in; (void)out_size; (void)ws_size;

    const float* query = (const float*)d_in[0];
    const float* value = (const float*)d_in[1];
    const float* prev  = (const float*)d_in[2];
    const float* convw = (const float*)d_in[3];
    const float* convb = (const float*)d_in[4];
    const float* Wq    = (const float*)d_in[5];
    const float* bq    = (const float*)d_in[6];
    const float* Wv    = (const float*)d_in[7];
    const float* Wloc  = (const float*)d_in[8];
    const float* bias  = (const float*)d_in[9];
    const float* Wout  = (const float*)d_in[10];
    const float* bout  = (const float*)d_in[11];
    const float* swq   = (const float*)d_in[12];
    const float* sbq   = (const float*)d_in[13];
    const float* swk   = (const float*)d_in[14];
    const float* sbk   = (const float*)d_in[15];
    const float* swv   = (const float*)d_in[16];
    const float* sbv   = (const float*)d_in[17];

    float* out_buf  = (float*)d_out;                          // (B,QL,HID) f32
    float* attn_buf = out_buf + (long long)B_ * QL_ * HID_;   // (64,512,512) f32

    float* ws = (float*)d_ws;
    // Region R3 (4194304 f): wqq/wvk/wvv f32 (early), then qqb bf16
    float*  wqq    = ws;
    float*  wvk    = ws + 1048576;
    float*  wvv    = ws + 2097152;
    ushort* qqb    = (ushort*)ws;
    // Region R1 (8388608 f): kk_f32, then vvT_b bf16
    float*  kk_f32 = ws + 4194304;
    ushort* vvT_b  = (ushort*)(ws + 4194304);
    // Region R2 (8388608 f): vv_f32, then attnb bf16
    float*  vv_f32 = ws + 12582912;
    ushort* attnb  = (ushort*)(ws + 12582912);
    // Acat bf16 (8192 x 2048): ctx | query
    ushort* Acat   = (ushort*)(ws + 20971520);
    // valueb bf16, then kkb bf16 (4194304 f region)
    ushort* valueb = (ushort*)(ws + 29360128);
    ushort* kkb    = valueb;
    // transposed bf16 weights
    ushort* wqqTb  = (ushort*)(ws + 33554432);
    ushort* wvkTb  = (ushort*)(ws + 34078720);
    ushort* wvvTb  = (ushort*)(ws + 34603008);
    ushort* WoutTb = (ushort*)(ws + 35127296);   // (1024 x 2048)
    float*  conv   = ws + 36175872;              // (64*512,10)
    float*  bqq    = ws + 36503552;
    float*  bkk    = bqq + 1024;
    float*  bvv    = bkk + 1024;
    float*  wlK    = bvv + 1024;
    float*  wlV    = wlK + 2560;

    // --- small precomputes ---
    conv_feats<<<dim3(64, 2), 256, 0, stream>>>(prev, convw, convb, conv);
    fold_bias<<<4, 256, 0, stream>>>(bq, sbq, swq, bias, sbk, swk, sbv, swv, bqq, bkk, bvv);
    fold_wloc<<<10, 256, 0, stream>>>(Wloc, swk, swv, wlK, wlV);

    // folded weights (f32): per head h, w**[:, h*256+d] = W[:, h*256+:] @ sw*
    gemm_f32<<<dim3(2, 8, 4), 256, 0, stream>>>(Wq, swq, wqq, nullptr, 1024, 256, 256,
        1024, 256, 1024, 256, 0, 0, 0, 256, 0, 4, 1.0f, 0);
    gemm_f32<<<dim3(2, 8, 4), 256, 0, stream>>>(Wv, swk, wvk, nullptr, 1024, 256, 256,
        1024, 256, 1024, 256, 0, 0, 0, 256, 0, 4, 1.0f, 0);
    gemm_f32<<<dim3(2, 8, 4), 256, 0, stream>>>(Wv, swv, wvv, nullptr, 1024, 256, 256,
        1024, 256, 1024, 256, 0, 0, 0, 256, 0, 4, 1.0f, 0);

    // transpose+cast weights to bf16 (N x K)
    transpose_cast<<<dim3(16, 16), 256, 0, stream>>>(wqq, wqqTb, 1024, 1024);
    transpose_cast<<<dim3(16, 16), 256, 0, stream>>>(wvk, wvkTb, 1024, 1024);
    transpose_cast<<<dim3(16, 16), 256, 0, stream>>>(wvv, wvvTb, 1024, 1024);
    transpose_cast<<<dim3(16, 32), 256, 0, stream>>>(Wout, WoutTb, 2048, 1024);

    // bf16 activations: query -> Acat right half; value -> valueb
    cast_rows<<<8192, 256, 0, stream>>>(query, Acat + 1024, 2048);
    cast_rows<<<8192, 256, 0, stream>>>(value, valueb, 1024);

    // qq = (query @ Wqq + bqq) / 16  -> bf16
    gemm_bf16<<<dim3(8, 64, 1), 256, 0, stream>>>(Acat + 1024, wqqTb, qqb, bqq,
        1024, 2048, 1024, 1024, 0, 0, 0, 0, 0, 0, 1, 0.0625f, 1);
    // kk = value @ Wvk + bkk -> f32 ; vv = value @ Wvv + bvv -> f32
    gemm_bf16<<<dim3(8, 64, 1), 256, 0, stream>>>(valueb, wvkTb, kk_f32, bkk,
        1024, 1024, 1024, 1024, 0, 0, 0, 0, 0, 0, 1, 1.0f, 0);
    gemm_bf16<<<dim3(8, 64, 1), 256, 0, stream>>>(valueb, wvvTb, vv_f32, bvv,
        1024, 1024, 1024, 1024, 0, 0, 0, 0, 0, 0, 1, 1.0f, 0);

    // rank-10 loc correction + bf16 cast (kk) / transpose (vv)
    finish_kk<<<8192, 256, 0, stream>>>(kk_f32, conv, wlK, kkb);
    finish_vvT<<<dim3(128, 16), 256, 0, stream>>>(vv_f32, conv, wlV, vvT_b);

    // scores = qqb @ kkb^T (scale already folded) -> attn f32 in d_out
    gemm_bf16<<<dim3(4, 4, 64), 256, 0, stream>>>(qqb, kkb, attn_buf, nullptr,
        256, 1024, 1024, 512,
        524288, 256, 524288, 256, 262144, 4194304, 16, 1.0f, 0);

    softmax_rows<<<32768, 256, 0, stream>>>(attn_buf, attnb);

    // ctx = attn @ vv -> bf16 into Acat left half (merged heads)
    gemm_bf16<<<dim3(2, 4, 64), 256, 0, stream>>>(attnb, vvT_b, Acat, nullptr,
        512, 512, 8192, 2048,
        262144, 4194304, 512, 2097152, 1048576, 256, 16, 1.0f, 1);

    // out = tanh([ctx | query] @ Wout + bout) -> f32
    gemm_bf16<<<dim3(8, 64, 1), 256, 0, stream>>>(Acat, WoutTb, out_buf, bout,
        2048, 2048, 2048, 1024, 0, 0, 0, 0, 0, 0, 1, 1.0f, 2);
}

// Round 4
// 500.073 us; speedup vs baseline: 3.5173x; 1.0643x over previous
//
#include <hip/hip_runtime.h>
#include <math.h>

// Problem constants
#define B_   16
#define QL_  512
#define VL_  512
#define HID_ 1024
#define NH_  4
#define CH_  10
#define DIM_ 256

typedef __attribute__((ext_vector_type(4))) float f32x4;
typedef __attribute__((ext_vector_type(8))) short bf16x8;

__device__ __forceinline__ ushort f2bf(float f) {
    union { float f; uint32_t u; } c; c.f = f;
    uint32_t u = c.u;
    u += 0x7fffu + ((u >> 16) & 1u);
    return (ushort)(u >> 16);
}

__device__ __forceinline__ void gload16(const void* g, void* l) {
    __builtin_amdgcn_global_load_lds((const __attribute__((address_space(1))) void*)g,
                                     (__attribute__((address_space(3))) void*)l,
                                     16, 0, 0);
}

// ================= MFMA bf16 GEMM: C = op((A @ Bt^T) + bias) * scale =================
// A: M x K bf16 row-major (lda). Bt: N x K bf16 row-major (ldb). Full tiles only.
// flags: 1 = C is bf16, 2 = tanh. batch z: zm=z%WB, zd=z/WB offsets.
// XCD-chunked bijective block swizzle (T1) within the x/y plane (all grids have nwg%8==0).
__global__ __launch_bounds__(256)
void gemm_bf16(const ushort* __restrict__ A, const ushort* __restrict__ Bt,
               void* __restrict__ Cv, const float* __restrict__ bias,
               int K, int lda, int ldb, int ldc,
               long long a1, long long a2, long long b1, long long b2,
               long long c1, long long c2, int WB,
               float post_scale, int flags)
{
    __shared__ ushort As[128 * 32];
    __shared__ ushort Bs[128 * 32];

    int z = blockIdx.z;
    int zm = z % WB, zd = z / WB;
    A  += a1 * zm + a2 * zd;
    Bt += b1 * zm + b2 * zd;
    long long coff = c1 * (long long)zm + c2 * (long long)zd;

    int gx = gridDim.x;
    int nwg = gx * gridDim.y;
    int flat = blockIdx.y * gx + blockIdx.x;
    int q = nwg >> 3, r = nwg & 7;
    int xcd = flat & 7, idx = flat >> 3;
    int logical = (xcd < r ? xcd * (q + 1) : r * (q + 1) + (xcd - r) * q) + idx;
    int brow = (logical / gx) * 128;
    int bcol = (logical % gx) * 128;

    int t = threadIdx.x;
    int lane = t & 63, w = t >> 6;
    int wr = (w >> 1) * 64, wc = (w & 1) * 64;

    const ushort* ga0 = A  + (long long)(brow + (t >> 2)) * lda + (t & 3) * 8;
    const ushort* ga1 = ga0 + (long long)64 * lda;
    const ushort* gb0 = Bt + (long long)(bcol + (t >> 2)) * ldb + (t & 3) * 8;
    const ushort* gb1 = gb0 + (long long)64 * ldb;
    ushort* la = As + t * 8;
    ushort* lb = Bs + t * 8;

    f32x4 acc[4][4] = {};

    for (int k0 = 0; k0 < K; k0 += 32) {
        gload16(ga0 + k0, la);
        gload16(ga1 + k0, la + 2048);
        gload16(gb0 + k0, lb);
        gload16(gb1 + k0, lb + 2048);
        __syncthreads();

        const bf16x8* ap = (const bf16x8*)(As + (wr + (lane & 15)) * 32 + (lane >> 4) * 8);
        const bf16x8* bp = (const bf16x8*)(Bs + (wc + (lane & 15)) * 32 + (lane >> 4) * 8);
        bf16x8 af[4], bfr[4];
        #pragma unroll
        for (int m = 0; m < 4; ++m) af[m] = ap[m * 64];
        #pragma unroll
        for (int n = 0; n < 4; ++n) bfr[n] = bp[n * 64];
        #pragma unroll
        for (int m = 0; m < 4; ++m)
            #pragma unroll
            for (int n = 0; n < 4; ++n)
                acc[m][n] = __builtin_amdgcn_mfma_f32_16x16x32_bf16(af[m], bfr[n], acc[m][n], 0, 0, 0);
        __syncthreads();
    }

    float*  Cf = (float*)Cv + coff;
    ushort* Cb = (ushort*)Cv + coff;
    #pragma unroll
    for (int m = 0; m < 4; ++m) {
        int r0 = brow + wr + m * 16 + (lane >> 4) * 4;
        #pragma unroll
        for (int n = 0; n < 4; ++n) {
            int c = bcol + wc + n * 16 + (lane & 15);
            float bv = bias ? bias[c] : 0.0f;
            #pragma unroll
            for (int j = 0; j < 4; ++j) {
                float v = (acc[m][n][j] + bv) * post_scale;
                if (flags & 2) v = tanhf(v);
                long long cidx = (long long)(r0 + j) * ldc + c;
                if (flags & 1) Cb[cidx] = f2bf(v);
                else           Cf[cidx] = v;
            }
        }
    }
}

// ================= f32 GEMM (tiny folded-weight products) =================
#define BM 128
#define BN 128
#define BK 8
__global__ __launch_bounds__(256)
void gemm_f32(const float* __restrict__ A, const float* __restrict__ B,
              float* __restrict__ C, const float* __restrict__ bias,
              int M, int N, int K, int lda, int ldb, int ldc,
              long long a1, long long a2, long long b1, long long b2,
              long long c1, long long c2, int WB,
              float scale, int flags)
{
    int z = blockIdx.z;
    int zm = z % WB, zd = z / WB;
    A += a1 * zm + a2 * zd;
    B += b1 * zm + b2 * zd;
    C += c1 * zm + c2 * zd;

    int brow = blockIdx.y * BM;
    int bcol = blockIdx.x * BN;

    __shared__ float As[BK][BM + 4];
    __shared__ float Bs[BK][BN + 4];

    int t  = threadIdx.x;
    int tx = t & 15;
    int ty = t >> 4;

    float acc[8][8] = {};

    int arow  = t >> 1;
    int apart = (t & 1) * 4;

    for (int k0 = 0; k0 < K; k0 += BK) {
        {
            const float* ap = A + (long long)(brow + arow) * lda + k0 + apart;
            float4 v = *(const float4*)ap;
            As[apart + 0][arow] = v.x;
            As[apart + 1][arow] = v.y;
            As[apart + 2][arow] = v.z;
            As[apart + 3][arow] = v.w;
        }
        if (!(flags & 4)) {
            int bro = t >> 5;
            int bco = (t & 31) * 4;
            const float* bp = B + (long long)(k0 + bro) * ldb + bcol + bco;
            float4 v = *(const float4*)bp;
            *(float4*)&Bs[bro][bco] = v;
        } else {
            int nrow = t >> 1;
            const float* bp = B + (long long)(bcol + nrow) * ldb + k0 + apart;
            float4 v = *(const float4*)bp;
            Bs[apart + 0][nrow] = v.x;
            Bs[apart + 1][nrow] = v.y;
            Bs[apart + 2][nrow] = v.z;
            Bs[apart + 3][nrow] = v.w;
        }
        __syncthreads();

        #pragma unroll
        for (int k = 0; k < BK; ++k) {
            float a[8], b[8];
            *(float4*)&a[0] = *(const float4*)&As[k][ty * 8];
            *(float4*)&a[4] = *(const float4*)&As[k][ty * 8 + 4];
            *(float4*)&b[0] = *(const float4*)&Bs[k][tx * 8];
            *(float4*)&b[4] = *(const float4*)&Bs[k][tx * 8 + 4];
            #pragma unroll
            for (int i = 0; i < 8; ++i)
                #pragma unroll
                for (int j = 0; j < 8; ++j)
                    acc[i][j] += a[i] * b[j];
        }
        __syncthreads();
    }

    #pragma unroll
    for (int i = 0; i < 8; ++i) {
        int r = brow + ty * 8 + i;
        #pragma unroll
        for (int j = 0; j < 8; ++j) {
            int c = bcol + tx * 8 + j;
            float vL = acc[i][j] * scale;
            if (bias) vL += bias[c];
            float* cp = C + (long long)r * ldc + c;
            if (flags & 1) vL += *cp;
            if (flags & 2) vL = tanhf(vL);
            *cp = vL;
        }
    }
}

// ================= small kernels =================
__global__ __launch_bounds__(256)
void conv_feats(const float* __restrict__ prev, const float* __restrict__ cw,
                const float* __restrict__ cb, float* __restrict__ out)
{
    int r = blockIdx.x;
    int l = blockIdx.y * 256 + threadIdx.x;
    const float* p = prev + (long long)r * VL_;
    float xm = (l > 0)       ? p[l - 1] : 0.f;
    float x0 = p[l];
    float xp = (l < VL_ - 1) ? p[l + 1] : 0.f;
    float* o = out + ((long long)r * VL_ + l) * CH_;
    #pragma unroll
    for (int c = 0; c < CH_; ++c)
        o[c] = xm * cw[c * 3 + 0] + x0 * cw[c * 3 + 1] + xp * cw[c * 3 + 2] + cb[c];
}

// bqq = bq_h@swq + sbq (1024) ; bkv = [bias_h@swk + sbk | bias_h@swv + sbv] (2048)
__global__ __launch_bounds__(256)
void fold_bias(const float* __restrict__ bq, const float* __restrict__ sbq, const float* __restrict__ swq,
               const float* __restrict__ bias, const float* __restrict__ sbk, const float* __restrict__ swk,
               const float* __restrict__ sbv, const float* __restrict__ swv,
               float* __restrict__ bqq, float* __restrict__ bkv)
{
    int idx = blockIdx.x * 256 + threadIdx.x;
    int h = idx >> 8, d = idx & 255;
    float s1 = 0.f, s2 = 0.f, s3 = 0.f;
    for (int j = 0; j < DIM_; ++j) {
        float bqj = bq[h * DIM_ + j];
        float bj  = bias[h * DIM_ + j];
        s1 += bqj * swq[j * DIM_ + d];
        s2 += bj  * swk[j * DIM_ + d];
        s3 += bj  * swv[j * DIM_ + d];
    }
    bqq[idx] = s1 + sbq[d];
    bkv[idx] = s2 + sbk[d];
    bkv[1024 + idx] = s3 + sbv[d];
}

__global__ __launch_bounds__(256)
void fold_wloc(const float* __restrict__ Wloc, const float* __restrict__ swk,
               const float* __restrict__ swv, float* __restrict__ WK, float* __restrict__ WV)
{
    int idx = blockIdx.x * 256 + threadIdx.x;
    int c = idx >> 8, d = idx & 255;
    float s1 = 0.f, s2 = 0.f;
    for (int j = 0; j < DIM_; ++j) {
        float w = Wloc[c * DIM_ + j];
        s1 += w * swk[j * DIM_ + d];
        s2 += w * swv[j * DIM_ + d];
    }
    WK[idx] = s1;
    WV[idx] = s2;
}

// cast 1024-col f32 rows to bf16 rows with output leading dim ld_out
__global__ __launch_bounds__(256)
void cast_rows(const float* __restrict__ in, ushort* __restrict__ out, int ld_out)
{
    long long idx = (long long)blockIdx.x * 256 + threadIdx.x;
    long long row = idx >> 8;
    int c4 = (int)(idx & 255) * 4;
    float4 v = *(const float4*)&in[row * 1024 + c4];
    ushort4 o;
    o.x = f2bf(v.x); o.y = f2bf(v.y); o.z = f2bf(v.z); o.w = f2bf(v.w);
    *(ushort4*)&out[row * ld_out + c4] = o;
}

// out[c][r] = bf16(in[r][c]); in: R x C f32 (ld C), out: C x R bf16 with ld_out. 64x64 tiles.
__global__ __launch_bounds__(256)
void transpose_cast(const float* __restrict__ in, ushort* __restrict__ out, int R, int C, int ld_out)
{
    __shared__ float tile[64][65];
    int r0 = blockIdx.y * 64, c0 = blockIdx.x * 64;
    int t = threadIdx.x;
    int tr = t >> 2, tc = (t & 3) * 16;
    const float* ip = in + (long long)(r0 + tr) * C + c0 + tc;
    #pragma unroll
    for (int i = 0; i < 4; ++i) {
        float4 v = *(const float4*)(ip + i * 4);
        tile[tr][tc + i * 4 + 0] = v.x;
        tile[tr][tc + i * 4 + 1] = v.y;
        tile[tr][tc + i * 4 + 2] = v.z;
        tile[tr][tc + i * 4 + 3] = v.w;
    }
    __syncthreads();
    int cl = t >> 2, rl = (t & 3) * 16;
    ushort* op = out + (long long)(c0 + cl) * ld_out + r0 + rl;
    #pragma unroll
    for (int i = 0; i < 16; ++i) op[i] = f2bf(tile[rl + i][cl]);
}

// bf16 transpose: out[c][r] = in[r][c]; in ld_in, out ld_out. 64x64 tiles.
__global__ __launch_bounds__(256)
void transpose_bf16(const ushort* __restrict__ in, ushort* __restrict__ out,
                    int ld_in, int ld_out)
{
    __shared__ ushort tile[64][72];
    int r0 = blockIdx.y * 64, c0 = blockIdx.x * 64;
    int t = threadIdx.x;
    int tr = t >> 2, tc = (t & 3) * 16;
    const ushort* ip = in + (long long)(r0 + tr) * ld_in + c0 + tc;
    *(bf16x8*)&tile[tr][tc]     = *(const bf16x8*)(ip);
    *(bf16x8*)&tile[tr][tc + 8] = *(const bf16x8*)(ip + 8);
    __syncthreads();
    int cl = t >> 2, rl = (t & 3) * 16;
    ushort v[16];
    #pragma unroll
    for (int i = 0; i < 16; ++i) v[i] = tile[rl + i][cl];
    ushort* op = out + (long long)(c0 + cl) * ld_out + r0 + rl;
    *(bf16x8*)op       = *(bf16x8*)&v[0];
    *(bf16x8*)(op + 8) = *(bf16x8*)&v[8];
}

// fill vext cols 1024..1087: conv features per (row, head, ch), zero pad
__global__ __launch_bounds__(256)
void vext_fill(const float* __restrict__ conv, ushort* __restrict__ vext)
{
    int idx = blockIdx.x * 256 + threadIdx.x;   // 8192*64
    int row = idx >> 6, j = idx & 63;
    int b = row >> 9, l = row & 511;
    ushort v = 0;
    if (j < 40) {
        int h = j / 10, c = j - h * 10;
        v = f2bf(conv[((long long)((b * 4 + h) * 512 + l)) * CH_ + c]);
    }
    vext[(long long)row * 1088 + 1024 + j] = v;
}

// fill btExt cols 1024..1087: wlK/wlV rows gated by head match
__global__ __launch_bounds__(256)
void btext_fill(const float* __restrict__ wlK, const float* __restrict__ wlV,
                ushort* __restrict__ btExt)
{
    int idx = blockIdx.x * 256 + threadIdx.x;   // 2048*64
    int n = idx >> 6, j = idx & 63;
    ushort v = 0;
    if (j < 40) {
        int hp = j / 10, c = j - hp * 10;
        int nn = n & 1023;
        int h = nn >> 8, d = nn & 255;
        if (hp == h) {
            const float* wl = (n >= 1024) ? wlV : wlK;
            v = f2bf(wl[c * 256 + d]);
        }
    }
    btExt[(long long)n * 1088 + 1024 + j] = v;
}

// row softmax over 512, in place (f32) + bf16 copy
__global__ __launch_bounds__(256)
void softmax_rows(float* __restrict__ s, ushort* __restrict__ sb)
{
    long long row = blockIdx.x;
    float* p = s + row * (long long)VL_;
    int t = threadIdx.x;
    float2 v = *(float2*)(p + 2 * t);

    float m = fmaxf(v.x, v.y);
    #pragma unroll
    for (int o = 32; o > 0; o >>= 1) m = fmaxf(m, __shfl_down(m, o));
    __shared__ float redm[4];
    __shared__ float reds[4];
    int wave = t >> 6, lane = t & 63;
    if (lane == 0) redm[wave] = m;
    __syncthreads();
    if (t == 0) redm[0] = fmaxf(fmaxf(redm[0], redm[1]), fmaxf(redm[2], redm[3]));
    __syncthreads();
    m = redm[0];

    float e0 = __expf(v.x - m), e1 = __expf(v.y - m);
    float sum = e0 + e1;
    #pragma unroll
    for (int o = 32; o > 0; o >>= 1) sum += __shfl_down(sum, o);
    if (lane == 0) reds[wave] = sum;
    __syncthreads();
    if (t == 0) reds[0] = reds[0] + reds[1] + reds[2] + reds[3];
    __syncthreads();
    float inv = 1.0f / reds[0];

    float2 o2;
    o2.x = e0 * inv;
    o2.y = e1 * inv;
    *(float2*)(p + 2 * t) = o2;
    ushort2 ob;
    ob.x = f2bf(o2.x); ob.y = f2bf(o2.y);
    *(ushort2*)&sb[row * VL_ + 2 * t] = ob;
}

extern "C" void kernel_launch(void* const* d_in, const int* in_sizes, int n_in,
                              void* d_out, int out_size, void* d_ws, size_t ws_size,
                              hipStream_t stream)
{
    (void)in_sizes; (void)n_in; (void)out_size; (void)ws_size;

    const float* query = (const float*)d_in[0];
    const float* value = (const float*)d_in[1];
    const float* prev  = (const float*)d_in[2];
    const float* convw = (const float*)d_in[3];
    const float* convb = (const float*)d_in[4];
    const float* Wq    = (const float*)d_in[5];
    const float* bq    = (const float*)d_in[6];
    const float* Wv    = (const float*)d_in[7];
    const float* Wloc  = (const float*)d_in[8];
    const float* bias  = (const float*)d_in[9];
    const float* Wout  = (const float*)d_in[10];
    const float* bout  = (const float*)d_in[11];
    const float* swq   = (const float*)d_in[12];
    const float* sbq   = (const float*)d_in[13];
    const float* swk   = (const float*)d_in[14];
    const float* sbk   = (const float*)d_in[15];
    const float* swv   = (const float*)d_in[16];
    const float* sbv   = (const float*)d_in[17];

    float* out_buf  = (float*)d_out;                          // (B,QL,HID) f32
    float* attn_buf = out_buf + (long long)B_ * QL_ * HID_;   // (64,512,512) f32

    // ---- workspace layout in BYTE offsets (liveness-verified, total 122.4 MB) ----
    // A [0, 17,825,792)            : vext 8192x1088 bf16  -> WoutTb 1024x2048 bf16 (after kkvv GEMM)
    // B [17,825,792, 51,380,224)   : kkvvb 8192x2048 bf16 -> attnb 64*512*512 bf16 (after scores)
    // C [51,380,224, 84,934,656)   : Acat 8192x2048 bf16 (ctx | query), live to end
    // D [84,934,656, 101,711,872)  : qqb 8192x1024 bf16
    // E [101,711,872, 118,983,424) : wqq/wvk/wvv f32 + btExt bf16 -> vvT_b 1024x8192 bf16
    // F [118,983,424, ...)         : conv f32, bqq, bkv, wlK, wlV, wqqTb
    char* wsb = (char*)d_ws;
    ushort* vext   = (ushort*)(wsb + 0);
    ushort* WoutTb = (ushort*)(wsb + 0);
    ushort* kkvvb  = (ushort*)(wsb + 17825792);
    ushort* attnb  = (ushort*)(wsb + 17825792);
    ushort* Acat   = (ushort*)(wsb + 51380224);
    ushort* qqb    = (ushort*)(wsb + 84934656);
    float*  wqq    = (float*)(wsb + 101711872);
    float*  wvk    = (float*)(wsb + 105906176);
    float*  wvv    = (float*)(wsb + 110100480);
    ushort* btExt  = (ushort*)(wsb + 114294784);
    ushort* vvT_b  = (ushort*)(wsb + 101711872);
    float*  conv   = (float*)(wsb + 118983424);
    float*  bqq    = (float*)(wsb + 120294144);
    float*  bkv    = (float*)(wsb + 120298240);
    float*  wlK    = (float*)(wsb + 120306432);
    float*  wlV    = (float*)(wsb + 120316672);
    ushort* wqqTb  = (ushort*)(wsb + 120326912);

    // --- small precomputes ---
    conv_feats<<<dim3(64, 2), 256, 0, stream>>>(prev, convw, convb, conv);
    fold_bias<<<4, 256, 0, stream>>>(bq, sbq, swq, bias, sbk, swk, sbv, swv, bqq, bkv);
    fold_wloc<<<10, 256, 0, stream>>>(Wloc, swk, swv, wlK, wlV);

    // folded weights (f32): w**[:, h*256+d] = W[:, h*256:] @ sw*
    gemm_f32<<<dim3(2, 8, 4), 256, 0, stream>>>(Wq, swq, wqq, nullptr, 1024, 256, 256,
        1024, 256, 1024, 256, 0, 0, 0, 256, 0, 4, 1.0f, 0);
    gemm_f32<<<dim3(2, 8, 4), 256, 0, stream>>>(Wv, swk, wvk, nullptr, 1024, 256, 256,
        1024, 256, 1024, 256, 0, 0, 0, 256, 0, 4, 1.0f, 0);
    gemm_f32<<<dim3(2, 8, 4), 256, 0, stream>>>(Wv, swv, wvv, nullptr, 1024, 256, 256,
        1024, 256, 1024, 256, 0, 0, 0, 256, 0, 4, 1.0f, 0);

    // transpose+cast weights to bf16 (N x K)
    transpose_cast<<<dim3(16, 16), 256, 0, stream>>>(wqq, wqqTb, 1024, 1024, 1024);
    transpose_cast<<<dim3(16, 16), 256, 0, stream>>>(wvk, btExt, 1024, 1024, 1088);
    transpose_cast<<<dim3(16, 16), 256, 0, stream>>>(wvv, btExt + (long long)1024 * 1088, 1024, 1024, 1088);
    btext_fill<<<512, 256, 0, stream>>>(wlK, wlV, btExt);

    // bf16 activations
    cast_rows<<<8192, 256, 0, stream>>>(query, Acat + 1024, 2048);
    cast_rows<<<8192, 256, 0, stream>>>(value, vext, 1088);
    vext_fill<<<2048, 256, 0, stream>>>(conv, vext);

    // qq = (query @ Wqq + bqq) / 16 -> bf16
    gemm_bf16<<<dim3(8, 64, 1), 256, 0, stream>>>(Acat + 1024, wqqTb, qqb, bqq,
        1024, 2048, 1024, 1024, 0, 0, 0, 0, 0, 0, 1, 0.0625f, 1);

    // kk|vv = [value|conv] @ [Wvk;wlK | Wvv;wlV] + bkv -> bf16 (loc folded via K-extension)
    gemm_bf16<<<dim3(16, 64, 1), 256, 0, stream>>>(vext, btExt, kkvvb, bkv,
        1088, 1088, 1088, 2048, 0, 0, 0, 0, 0, 0, 1, 1.0f, 1);

    // Wout^T bf16 into region A (vext dead now)
    transpose_cast<<<dim3(16, 32), 256, 0, stream>>>(Wout, WoutTb, 2048, 1024, 2048);

    // vvT = transpose of vv half of kkvvb: (1024 x 8192) into region E (w*/btExt dead)
    transpose_bf16<<<dim3(16, 128), 256, 0, stream>>>(kkvvb + 1024, vvT_b, 2048, 8192);

    // scores = qqb @ kk^T (scale pre-folded) -> attn f32 in d_out
    gemm_bf16<<<dim3(4, 4, 64), 256, 0, stream>>>(qqb, kkvvb, attn_buf, nullptr,
        256, 1024, 2048, 512,
        524288, 256, 1048576, 256, 262144, 4194304, 16, 1.0f, 0);

    // softmax (f32 in d_out) + bf16 copy into region B (kkvvb dead now)
    softmax_rows<<<32768, 256, 0, stream>>>(attn_buf, attnb);

    // ctx = attn @ vv -> bf16 into Acat left half (merged heads)
    gemm_bf16<<<dim3(2, 4, 64), 256, 0, stream>>>(attnb, vvT_b, Acat, nullptr,
        512, 512, 8192, 2048,
        262144, 4194304, 512, 2097152, 1048576, 256, 16, 1.0f, 1);

    // out = tanh([ctx | query] @ Wout + bout) -> f32
    gemm_bf16<<<dim3(8, 64, 1), 256, 0, stream>>>(Acat, WoutTb, out_buf, bout,
        2048, 2048, 2048, 1024, 0, 0, 0, 0, 0, 0, 1, 1.0f, 2);
}

// Round 5
// 300.738 us; speedup vs baseline: 5.8487x; 1.6628x over previous
//
#include <hip/hip_runtime.h>
#include <math.h>

// Problem constants
#define B_   16
#define QL_  512
#define VL_  512
#define HID_ 1024
#define NH_  4
#define CH_  10
#define DIM_ 256

typedef __attribute__((ext_vector_type(4))) float f32x4;
typedef __attribute__((ext_vector_type(8))) short bf16x8;

__device__ __forceinline__ ushort f2bf(float f) {
    union { float f; uint32_t u; } c; c.f = f;
    uint32_t u = c.u;
    u += 0x7fffu + ((u >> 16) & 1u);
    return (ushort)(u >> 16);
}

__device__ __forceinline__ void gload16(const void* g, void* l) {
    __builtin_amdgcn_global_load_lds((const __attribute__((address_space(1))) void*)g,
                                     (__attribute__((address_space(3))) void*)l,
                                     16, 0, 0);
}

// ================= MFMA bf16 GEMM, 2-phase pipelined, BK=64, XOR-swizzled LDS ==========
// C = op((A @ Bt^T) + bias) * scale. A: M x K bf16 (lda). Bt: N x K bf16 (ldb).
// M%128==0, N%128==0, K%64==0. flags: 1 = bf16 C, 2 = tanh,
// 8 = kkvv split mode: cols<1024 -> Cv (ldc), cols>=1024 -> Cv2 transposed (ld 8192).
// Swizzle: LDS slot s of row r holds global k-granule (s ^ (r&7)); stage permutes the
// GLOBAL source address (linear LDS dest for global_load_lds), read applies same XOR.
__global__ __launch_bounds__(256)
void gemm_bf16(const ushort* __restrict__ A, const ushort* __restrict__ Bt,
               void* __restrict__ Cv, void* __restrict__ Cv2,
               const float* __restrict__ bias,
               int K, int lda, int ldb, int ldc,
               long long a1, long long a2, long long b1, long long b2,
               long long c1, long long c2, int WB,
               float post_scale, int flags)
{
    __shared__ ushort As[2][128 * 64];
    __shared__ ushort Bs[2][128 * 64];

    int z = blockIdx.z;
    int zm = z % WB, zd = z / WB;
    A  += a1 * zm + a2 * zd;
    Bt += b1 * zm + b2 * zd;
    long long coff = c1 * (long long)zm + c2 * (long long)zd;

    // XCD-aware bijective chunked swizzle (T1)
    int gx = gridDim.x;
    int nwg = gx * gridDim.y;
    int flat = blockIdx.y * gx + blockIdx.x;
    int q = nwg >> 3, r = nwg & 7;
    int xcd = flat & 7, idx = flat >> 3;
    int logical = (xcd < r ? xcd * (q + 1) : r * (q + 1) + (xcd - r) * q) + idx;
    int brow = (logical / gx) * 128;
    int bcol = (logical % gx) * 128;

    int t = threadIdx.x;
    int lane = t & 63, w = t >> 6;
    int wr = (w >> 1) * 64, wc = (w & 1) * 64;

    // staging: chunk = i*256 + t, row = chunk>>3 (= srow + i*32), slot = t&7.
    // (row&7) == (srow&7) for all i since 32%8==0 -> single source permutation.
    int srow  = t >> 3;
    int sslot = t & 7;
    int sk = ((sslot ^ (srow & 7)) << 3);
    const ushort* gaBase = A  + (long long)(brow + srow) * lda + sk;
    const ushort* gbBase = Bt + (long long)(bcol + srow) * ldb + sk;

    f32x4 acc[4][4] = {};

    auto stage = [&](int buf, int k0) {
        ushort* la = &As[buf][t * 8];
        ushort* lb = &Bs[buf][t * 8];
        #pragma unroll
        for (int i = 0; i < 4; ++i) {
            gload16(gaBase + (long long)(i * 32) * lda + k0, la + i * 2048);
            gload16(gbBase + (long long)(i * 32) * ldb + k0, lb + i * 2048);
        }
    };

    int NT = K >> 6;
    stage(0, 0);
    __syncthreads();                       // vmcnt(0) drain + barrier: tile 0 ready
    int cur = 0;
    for (int tI = 0; tI < NT; ++tI) {
        if (tI + 1 < NT) stage(cur ^ 1, (tI + 1) << 6);   // prefetch under compute
        #pragma unroll
        for (int kk = 0; kk < 2; ++kk) {
            int slot = ((kk << 2) + (lane >> 4)) ^ (lane & 7);   // row&7 == lane&7 here
            const ushort* ab = &As[cur][(wr + (lane & 15)) * 64 + slot * 8];
            const ushort* bb = &Bs[cur][(wc + (lane & 15)) * 64 + slot * 8];
            bf16x8 af[4], bfr[4];
            #pragma unroll
            for (int m = 0; m < 4; ++m) af[m]  = *(const bf16x8*)(ab + m * 1024);
            #pragma unroll
            for (int n = 0; n < 4; ++n) bfr[n] = *(const bf16x8*)(bb + n * 1024);
            #pragma unroll
            for (int m = 0; m < 4; ++m)
                #pragma unroll
                for (int n = 0; n < 4; ++n)
                    acc[m][n] = __builtin_amdgcn_mfma_f32_16x16x32_bf16(af[m], bfr[n], acc[m][n], 0, 0, 0);
        }
        __syncthreads();                   // reads done; next stage's loads landed
        cur ^= 1;
    }

    float*  Cf = (float*)Cv + coff;
    ushort* Cb = (ushort*)Cv + coff;
    ushort* C2 = (ushort*)Cv2;
    #pragma unroll
    for (int m = 0; m < 4; ++m) {
        int r0 = brow + wr + m * 16 + (lane >> 4) * 4;
        #pragma unroll
        for (int n = 0; n < 4; ++n) {
            int c = bcol + wc + n * 16 + (lane & 15);
            float bv = bias ? bias[c] : 0.0f;
            float v0 = (acc[m][n][0] + bv) * post_scale;
            float v1 = (acc[m][n][1] + bv) * post_scale;
            float v2 = (acc[m][n][2] + bv) * post_scale;
            float v3 = (acc[m][n][3] + bv) * post_scale;
            if (flags & 2) { v0 = tanhf(v0); v1 = tanhf(v1); v2 = tanhf(v2); v3 = tanhf(v3); }
            if ((flags & 8) && c >= 1024) {
                ushort4 o;
                o.x = f2bf(v0); o.y = f2bf(v1); o.z = f2bf(v2); o.w = f2bf(v3);
                *(ushort4*)&C2[(long long)(c - 1024) * 8192 + r0] = o;
            } else if (flags & 1) {
                Cb[(long long)(r0 + 0) * ldc + c] = f2bf(v0);
                Cb[(long long)(r0 + 1) * ldc + c] = f2bf(v1);
                Cb[(long long)(r0 + 2) * ldc + c] = f2bf(v2);
                Cb[(long long)(r0 + 3) * ldc + c] = f2bf(v3);
            } else {
                Cf[(long long)(r0 + 0) * ldc + c] = v0;
                Cf[(long long)(r0 + 1) * ldc + c] = v1;
                Cf[(long long)(r0 + 2) * ldc + c] = v2;
                Cf[(long long)(r0 + 3) * ldc + c] = v3;
            }
        }
    }
}

// ================= small kernels =================
// fused: conv1d features -> vext cols 1024..1087 (bf16), zero pad
__global__ __launch_bounds__(256)
void vext_fill_conv(const float* __restrict__ prev, const float* __restrict__ cw,
                    const float* __restrict__ cb, ushort* __restrict__ vext)
{
    int idx = blockIdx.x * 256 + threadIdx.x;   // 8192*64
    int row = idx >> 6, j = idx & 63;
    int b = row >> 9, l = row & 511;
    ushort v = 0;
    if (j < 40) {
        int h = j / 10, c = j - h * 10;
        const float* p = prev + (long long)(b * 4 + h) * VL_;
        float xm = (l > 0)       ? p[l - 1] : 0.f;
        float x0 = p[l];
        float xp = (l < VL_ - 1) ? p[l + 1] : 0.f;
        v = f2bf(xm * cw[c * 3 + 0] + x0 * cw[c * 3 + 1] + xp * cw[c * 3 + 2] + cb[c]);
    }
    vext[(long long)row * 1088 + 1024 + j] = v;
}

// merged bias/wloc folds: bqq(1024), bkv(2048), wlK(2560), wlV(2560)
__global__ __launch_bounds__(256)
void fold_small(const float* __restrict__ bq, const float* __restrict__ sbq, const float* __restrict__ swq,
                const float* __restrict__ bias, const float* __restrict__ sbk, const float* __restrict__ swk,
                const float* __restrict__ sbv, const float* __restrict__ swv,
                const float* __restrict__ Wloc,
                float* __restrict__ bqq, float* __restrict__ bkv,
                float* __restrict__ wlK, float* __restrict__ wlV)
{
    int idx = blockIdx.x * 256 + threadIdx.x;   // grid 32 -> 0..8191
    if (idx < 1024) {
        int h = idx >> 8, d = idx & 255;
        float s = 0.f;
        for (int j = 0; j < 256; ++j) s += bq[h * 256 + j] * swq[j * 256 + d];
        bqq[idx] = s + sbq[d];
    } else if (idx < 3072) {
        int i = idx - 1024;
        int kv = i >> 10, ii = i & 1023;
        int h = ii >> 8, d = ii & 255;
        const float* sw = kv ? swv : swk;
        const float* sb = kv ? sbv : sbk;
        float s = 0.f;
        for (int j = 0; j < 256; ++j) s += bias[h * 256 + j] * sw[j * 256 + d];
        bkv[i] = s + sb[d];
    } else if (idx < 5632) {
        int i = idx - 3072; int c = i >> 8, d = i & 255;
        float s = 0.f;
        for (int j = 0; j < 256; ++j) s += Wloc[c * 256 + j] * swk[j * 256 + d];
        wlK[i] = s;
    } else if (idx < 8192) {
        int i = idx - 5632; int c = i >> 8, d = i & 255;
        float s = 0.f;
        for (int j = 0; j < 256; ++j) s += Wloc[c * 256 + j] * swv[j * 256 + d];
        wlV[i] = s;
    }
}

// cast 1024-col f32 rows to bf16 rows with output leading dim ld_out (one row per block)
__global__ __launch_bounds__(256)
void cast_rows(const float* __restrict__ in, ushort* __restrict__ out, int ld_out)
{
    long long idx = (long long)blockIdx.x * 256 + threadIdx.x;
    long long row = idx >> 8;
    int c4 = (int)(idx & 255) * 4;
    float4 v = *(const float4*)&in[row * 1024 + c4];
    ushort4 o;
    o.x = f2bf(v.x); o.y = f2bf(v.y); o.z = f2bf(v.z); o.w = f2bf(v.w);
    *(ushort4*)&out[row * ld_out + c4] = o;
}

// out[c][r] = bf16(in[r][c]); in: R x C f32, out: C x R bf16 (ld_out). 64x64 tiles.
__global__ __launch_bounds__(256)
void transpose_cast(const float* __restrict__ in, ushort* __restrict__ out, int R, int C, int ld_out)
{
    __shared__ float tile[64][65];
    int r0 = blockIdx.y * 64, c0 = blockIdx.x * 64;
    int t = threadIdx.x;
    int tr = t >> 2, tc = (t & 3) * 16;
    const float* ip = in + (long long)(r0 + tr) * C + c0 + tc;
    #pragma unroll
    for (int i = 0; i < 4; ++i) {
        float4 v = *(const float4*)(ip + i * 4);
        tile[tr][tc + i * 4 + 0] = v.x;
        tile[tr][tc + i * 4 + 1] = v.y;
        tile[tr][tc + i * 4 + 2] = v.z;
        tile[tr][tc + i * 4 + 3] = v.w;
    }
    __syncthreads();
    int cl = t >> 2, rl = (t & 3) * 16;
    ushort* op = out + (long long)(c0 + cl) * ld_out + r0 + rl;
    #pragma unroll
    for (int i = 0; i < 16; ++i) op[i] = f2bf(tile[rl + i][cl]);
}

// transpose+cast the three 256x256 score-proj weights in one launch (z selects)
__global__ __launch_bounds__(256)
void sw3_transpose(const float* __restrict__ swq, const float* __restrict__ swk,
                   const float* __restrict__ swv, ushort* __restrict__ oq,
                   ushort* __restrict__ ok, ushort* __restrict__ ov)
{
    __shared__ float tile[64][65];
    const float* in = (blockIdx.z == 0) ? swq : (blockIdx.z == 1) ? swk : swv;
    ushort* out     = (blockIdx.z == 0) ? oq  : (blockIdx.z == 1) ? ok  : ov;
    int r0 = blockIdx.y * 64, c0 = blockIdx.x * 64;
    int t = threadIdx.x;
    int tr = t >> 2, tc = (t & 3) * 16;
    const float* ip = in + (long long)(r0 + tr) * 256 + c0 + tc;
    #pragma unroll
    for (int i = 0; i < 4; ++i) {
        float4 v = *(const float4*)(ip + i * 4);
        tile[tr][tc + i * 4 + 0] = v.x;
        tile[tr][tc + i * 4 + 1] = v.y;
        tile[tr][tc + i * 4 + 2] = v.z;
        tile[tr][tc + i * 4 + 3] = v.w;
    }
    __syncthreads();
    int cl = t >> 2, rl = (t & 3) * 16;
    ushort* op = out + (long long)(c0 + cl) * 256 + r0 + rl;
    #pragma unroll
    for (int i = 0; i < 16; ++i) op[i] = f2bf(tile[rl + i][cl]);
}

// fill btExt cols 1024..1087: wlK/wlV rows gated by head match
__global__ __launch_bounds__(256)
void btext_fill(const float* __restrict__ wlK, const float* __restrict__ wlV,
                ushort* __restrict__ btExt)
{
    int idx = blockIdx.x * 256 + threadIdx.x;   // 2048*64
    int n = idx >> 6, j = idx & 63;
    ushort v = 0;
    if (j < 40) {
        int hp = j / 10, c = j - hp * 10;
        int nn = n & 1023;
        int h = nn >> 8, d = nn & 255;
        if (hp == h) {
            const float* wl = (n >= 1024) ? wlV : wlK;
            v = f2bf(wl[c * 256 + d]);
        }
    }
    btExt[(long long)n * 1088 + 1024 + j] = v;
}

// row softmax over 512, in place (f32) + bf16 copy
__global__ __launch_bounds__(256)
void softmax_rows(float* __restrict__ s, ushort* __restrict__ sb)
{
    long long row = blockIdx.x;
    float* p = s + row * (long long)VL_;
    int t = threadIdx.x;
    float2 v = *(float2*)(p + 2 * t);

    float m = fmaxf(v.x, v.y);
    #pragma unroll
    for (int o = 32; o > 0; o >>= 1) m = fmaxf(m, __shfl_down(m, o));
    __shared__ float redm[4];
    __shared__ float reds[4];
    int wave = t >> 6, lane = t & 63;
    if (lane == 0) redm[wave] = m;
    __syncthreads();
    if (t == 0) redm[0] = fmaxf(fmaxf(redm[0], redm[1]), fmaxf(redm[2], redm[3]));
    __syncthreads();
    m = redm[0];

    float e0 = __expf(v.x - m), e1 = __expf(v.y - m);
    float sum = e0 + e1;
    #pragma unroll
    for (int o = 32; o > 0; o >>= 1) sum += __shfl_down(sum, o);
    if (lane == 0) reds[wave] = sum;
    __syncthreads();
    if (t == 0) reds[0] = reds[0] + reds[1] + reds[2] + reds[3];
    __syncthreads();
    float inv = 1.0f / reds[0];

    float2 o2;
    o2.x = e0 * inv;
    o2.y = e1 * inv;
    *(float2*)(p + 2 * t) = o2;
    ushort2 ob;
    ob.x = f2bf(o2.x); ob.y = f2bf(o2.y);
    *(ushort2*)&sb[row * VL_ + 2 * t] = ob;
}

extern "C" void kernel_launch(void* const* d_in, const int* in_sizes, int n_in,
                              void* d_out, int out_size, void* d_ws, size_t ws_size,
                              hipStream_t stream)
{
    (void)in_sizes; (void)n_in; (void)out_size; (void)ws_size;

    const float* query = (const float*)d_in[0];
    const float* value = (const float*)d_in[1];
    const float* prev  = (const float*)d_in[2];
    const float* convw = (const float*)d_in[3];
    const float* convb = (const float*)d_in[4];
    const float* Wq    = (const float*)d_in[5];
    const float* bq    = (const float*)d_in[6];
    const float* Wv    = (const float*)d_in[7];
    const float* Wloc  = (const float*)d_in[8];
    const float* bias  = (const float*)d_in[9];
    const float* Wout  = (const float*)d_in[10];
    const float* bout  = (const float*)d_in[11];
    const float* swq   = (const float*)d_in[12];
    const float* sbq   = (const float*)d_in[13];
    const float* swk   = (const float*)d_in[14];
    const float* sbk   = (const float*)d_in[15];
    const float* swv   = (const float*)d_in[16];
    const float* sbv   = (const float*)d_in[17];

    float* out_buf  = (float*)d_out;                          // (B,QL,HID) f32
    float* attn_buf = out_buf + (long long)B_ * QL_ * HID_;   // (64,512,512) f32

    // ---- workspace layout, BYTE offsets (liveness-audited, total 130.2 MB) ----
    char* wsb = (char*)d_ws;
    ushort* vext   = (ushort*)(wsb + 0);           // 8192x1088 bf16 (17,825,792 B)
    ushort* WoutTb = (ushort*)(wsb + 0);           // 1024x2048 bf16, after kkvv
    ushort* kkb    = (ushort*)(wsb + 17825792);    // 8192x1024 bf16
    ushort* attnb  = (ushort*)(wsb + 17825792);    // 64*512*512 bf16, after scores
    ushort* Acat   = (ushort*)(wsb + 51380224);    // 8192x2048 bf16 (ctx | query)
    ushort* qqb    = (ushort*)(wsb + 84934656);    // 8192x1024 bf16
    ushort* vvT_b  = (ushort*)(wsb + 101711872);   // 1024x8192 bf16
    float*  bqq    = (float*)(wsb + 118983424);
    float*  bkv    = (float*)(wsb + 118987520);
    float*  wlK    = (float*)(wsb + 118995712);
    float*  wlV    = (float*)(wsb + 119005952);
    ushort* swqTb  = (ushort*)(wsb + 119016192);   // 256x256 bf16
    ushort* swkTb  = (ushort*)(wsb + 119147264);
    ushort* swvTb  = (ushort*)(wsb + 119278336);
    ushort* Wqb    = (ushort*)(wsb + 119409408);   // 1024x1024 bf16
    ushort* Wvb    = (ushort*)(wsb + 121506560);   // 1024x1024 bf16
    ushort* wqqTb  = (ushort*)(wsb + 123603712);   // 1024x1024 bf16
    ushort* btExt  = (ushort*)(wsb + 125700864);   // 2048x1088 bf16

    // --- precomputes (input-only deps) ---
    fold_small<<<32, 256, 0, stream>>>(bq, sbq, swq, bias, sbk, swk, sbv, swv, Wloc,
                                       bqq, bkv, wlK, wlV);
    vext_fill_conv<<<2048, 256, 0, stream>>>(prev, convw, convb, vext);
    cast_rows<<<1024, 256, 0, stream>>>(Wq, Wqb, 1024);
    cast_rows<<<1024, 256, 0, stream>>>(Wv, Wvb, 1024);
    sw3_transpose<<<dim3(4, 4, 3), 256, 0, stream>>>(swq, swk, swv, swqTb, swkTb, swvTb);
    cast_rows<<<8192, 256, 0, stream>>>(query, Acat + 1024, 2048);
    cast_rows<<<8192, 256, 0, stream>>>(value, vext, 1088);

    // folded weights via MFMA: wT[h*256+d][k] = sum_j sw[j][d] * W[k][h*256+j]
    gemm_bf16<<<dim3(8, 2, 4), 256, 0, stream>>>(swqTb, Wqb, wqqTb, nullptr, nullptr,
        256, 256, 1024, 1024, 0, 0, 0, 256, 0, 262144, 1, 1.0f, 1);
    gemm_bf16<<<dim3(8, 2, 4), 256, 0, stream>>>(swkTb, Wvb, btExt, nullptr, nullptr,
        256, 256, 1024, 1088, 0, 0, 0, 256, 0, 278528, 1, 1.0f, 1);
    gemm_bf16<<<dim3(8, 2, 4), 256, 0, stream>>>(swvTb, Wvb, btExt + (long long)1024 * 1088, nullptr, nullptr,
        256, 256, 1024, 1088, 0, 0, 0, 256, 0, 278528, 1, 1.0f, 1);
    btext_fill<<<512, 256, 0, stream>>>(wlK, wlV, btExt);

    // qq = (query @ Wqq + bqq) / 16 -> bf16
    gemm_bf16<<<dim3(8, 64, 1), 256, 0, stream>>>(Acat + 1024, wqqTb, qqb, nullptr, bqq,
        1024, 2048, 1024, 1024, 0, 0, 0, 0, 0, 0, 1, 0.0625f, 1);

    // kk|vv = [value|conv] @ [Wvk;wlK | Wvv;wlV] + bkv; kk -> kkb, vv -> vvT (transposed)
    gemm_bf16<<<dim3(16, 64, 1), 256, 0, stream>>>(vext, btExt, kkb, vvT_b, bkv,
        1088, 1088, 1088, 1024, 0, 0, 0, 0, 0, 0, 1, 1.0f, 1 | 8);

    // Wout^T bf16 into region A (vext dead after kkvv)
    transpose_cast<<<dim3(16, 32), 256, 0, stream>>>(Wout, WoutTb, 2048, 1024, 2048);

    // scores = qqb @ kk^T (1/16 pre-folded) -> attn f32 in d_out
    gemm_bf16<<<dim3(4, 4, 64), 256, 0, stream>>>(qqb, kkb, attn_buf, nullptr, nullptr,
        256, 1024, 1024, 512,
        524288, 256, 524288, 256, 262144, 4194304, 16, 1.0f, 0);

    // softmax (f32 in d_out) + bf16 copy into region B (kkb dead)
    softmax_rows<<<32768, 256, 0, stream>>>(attn_buf, attnb);

    // ctx = attn @ vv -> bf16 into Acat left half (merged heads)
    gemm_bf16<<<dim3(2, 4, 64), 256, 0, stream>>>(attnb, vvT_b, Acat, nullptr, nullptr,
        512, 512, 8192, 2048,
        262144, 4194304, 512, 2097152, 1048576, 256, 16, 1.0f, 1);

    // out = tanh([ctx | query] @ Wout + bout) -> f32
    gemm_bf16<<<dim3(8, 64, 1), 256, 0, stream>>>(Acat, WoutTb, out_buf, nullptr, bout,
        2048, 2048, 2048, 1024, 0, 0, 0, 0, 0, 0, 1, 1.0f, 2);
}